// Round 4
// baseline (1567.050 us; speedup 1.0000x reference)
//
#include <hip/hip_runtime.h>

// GINE 2-layer GNN: N=50000 nodes, E=800000 edges, d=128, f32.
// Round 4: bucket-based edge pipeline.
//  - scatter_edges had 8x write amplification (52.7MB HBM writes for 6.4MB
//    payload, 0.95 TB/s effective). Replace CSR scatter with a counting sort
//    into 64-node buckets: per-(chunk,bucket) writes are contiguous runs.
//  - aggregate was latency-bound (serial 16-edge loop, 1-deep prefetch).
//    Replace with per-bucket edge-PARALLEL aggregation: 1 wave per edge,
//    4-deep unroll, LDS f32 atomic accumulate (2-way bank alias = free),
//    dense 32KB writeout. No CSR offsets needed anywhere -> count_deg and
//    the node-level scan kernels are deleted.
//  - GEMM unchanged from round 3.

typedef unsigned long long u64;
typedef unsigned int u32;

constexpr int NN = 50000;
constexpr int NE = 800000;
constexpr int D  = 128;
constexpr int RPB = 32;                   // rows per block in the GEMM
constexpr int BSH = 6;                    // 64 nodes per bucket
constexpr int NB  = (NN + 63) >> BSH;     // 782 buckets
constexpr int NC  = 128;                  // edge chunks
constexpr int CHUNK = NE / NC;            // 6250 (exact)

// pack: [wt f32 | 9 spare | dst6 (6b) | src (17b)]
__device__ __forceinline__ u64 pack_edge(int src, int d6, float w) {
    return ((u64)__float_as_uint(w) << 32) | (u32)(src | (d6 << 17));
}

// ---------------- bucket sort build ----------------

__global__ __launch_bounds__(256) void hist(
    const int* __restrict__ dst, int* __restrict__ G)
{
    __shared__ int hh[NB];
    int t = threadIdx.x, c = blockIdx.x;
    for (int i = t; i < NB; i += 256) hh[i] = 0;
    __syncthreads();
    int e0 = c * CHUNK;
    for (int i = t; i < CHUNK; i += 256)
        atomicAdd(&hh[dst[e0 + i] >> BSH], 1);
    __syncthreads();
    for (int i = t; i < NB; i += 256) G[c * NB + i] = hh[i];
}

// per-bucket serial scan over the NC chunks (loads are independent -> pipelined)
__global__ __launch_bounds__(256) void colscan(
    const int* __restrict__ G, int* __restrict__ O, int* __restrict__ S)
{
    int b = blockIdx.x * 256 + threadIdx.x;
    if (b >= NB) return;
    int run = 0;
    #pragma unroll 16
    for (int c = 0; c < NC; ++c) {
        int g = G[c * NB + b];
        O[c * NB + b] = run;
        run += g;
    }
    S[b] = run;
}

// one block: exclusive scan of S[0..NB) -> B, B[NB] = NE
__global__ __launch_bounds__(1024) void scanS(
    const int* __restrict__ S, int* __restrict__ B)
{
    __shared__ int s[1024];
    int t = threadIdx.x;
    int v = (t < NB) ? S[t] : 0;
    s[t] = v;
    __syncthreads();
    for (int d = 1; d < 1024; d <<= 1) {
        int u = (t >= d) ? s[t - d] : 0;
        __syncthreads();
        s[t] += u;
        __syncthreads();
    }
    if (t < NB) B[t] = s[t] - v;
    if (t == 0) B[NB] = NE;
}

__global__ __launch_bounds__(256) void bucket_scatter(
    const int*   __restrict__ src,
    const int*   __restrict__ dst,
    const float* __restrict__ ew,
    const int*   __restrict__ O,
    const int*   __restrict__ B,
    u64*         __restrict__ stage)
{
    __shared__ int base_s[NB];
    __shared__ int cnt_s[NB];
    int t = threadIdx.x, c = blockIdx.x;
    for (int i = t; i < NB; i += 256) {
        base_s[i] = B[i] + O[c * NB + i];
        cnt_s[i]  = 0;
    }
    __syncthreads();
    int e0 = c * CHUNK;
    for (int i = t; i < CHUNK; i += 256) {
        int e  = e0 + i;
        int d  = dst[e];
        int bk = d >> BSH;
        int r  = atomicAdd(&cnt_s[bk], 1);
        stage[base_s[bk] + r] = pack_edge(src[e], d & 63, ew[e]);
    }
}

// ---------------- per-layer aggregate (edge-parallel, LDS accumulate) ------

__global__ __launch_bounds__(256) void bucket_aggregate(
    const float* __restrict__ h,
    const int*   __restrict__ B,
    const u64*   __restrict__ stage,
    const float* __restrict__ We,
    const float* __restrict__ be,
    float*       __restrict__ agg)
{
    __shared__ float acc[64 * D];           // 32 KB
    const int t = threadIdx.x;
    const int b = blockIdx.x;
    const int lane = t & 63;
    const int wv   = t >> 6;                // wave id 0..3

    for (int i = t; i < 64 * D; i += 256) acc[i] = 0.f;

    const float we0 = We[lane], we1 = We[lane + 64];
    const float be0 = be[lane], be1 = be[lane + 64];
    const int e0 = B[b], e1 = B[b + 1];
    __syncthreads();

    for (int eb = e0 + wv * 4; eb < e1; eb += 16) {
        int m = e1 - eb; if (m > 4) m = 4;   // wave-uniform
        u64 p[4];
        #pragma unroll
        for (int k = 0; k < 4; ++k) p[k] = (k < m) ? stage[eb + k] : 0;
        float h0[4], h1[4];
        #pragma unroll
        for (int k = 0; k < 4; ++k) {
            int s = (int)(p[k] & 0x1FFFF);
            const float* hp = h + (size_t)s * D + lane;
            h0[k] = (k < m) ? hp[0]  : 0.f;
            h1[k] = (k < m) ? hp[64] : 0.f;
        }
        #pragma unroll
        for (int k = 0; k < 4; ++k) {
            if (k < m) {
                float w  = __uint_as_float((u32)(p[k] >> 32));
                int   d6 = (int)((p[k] >> 17) & 63);
                float m0 = fmaxf(0.f, h0[k] + fmaf(w, we0, be0));
                float m1 = fmaxf(0.f, h1[k] + fmaf(w, we1, be1));
                atomicAdd(&acc[d6 * D + lane],      m0);
                atomicAdd(&acc[d6 * D + 64 + lane], m1);
            }
        }
    }
    __syncthreads();

    const int n0 = b << BSH;
    for (int i = t; i < 64 * D; i += 256) {
        int node = n0 + (i >> 7);
        if (node < NN) agg[(size_t)node * D + (i & 127)] = acc[i];
    }
}

// ---------------- GEMM: out = (relu?)((A1+A2) @ W + bias) ----------------

__global__ __launch_bounds__(256) void gemm_add_bias(
    const float* __restrict__ A1,
    const float* __restrict__ A2,
    const float* __restrict__ W,
    const float* __restrict__ bias,
    float*       __restrict__ out,
    int relu)
{
    __shared__ float Ws[64 * D];        // half of W at a time: 32 KB
    __shared__ float As[RPB][D + 4];

    const int t    = threadIdx.x;
    const int row0 = blockIdx.x * RPB;

    for (int i = t; i < RPB * (D / 4); i += 256) {
        int r   = i >> 5;
        int c4  = (i & 31) << 2;
        int row = row0 + r;
        float4 v = make_float4(0.f, 0.f, 0.f, 0.f);
        if (row < NN) {
            float4 v1 = *(const float4*)(A1 + (size_t)row * D + c4);
            float4 v2 = *(const float4*)(A2 + (size_t)row * D + c4);
            v = make_float4(v1.x + v2.x, v1.y + v2.y, v1.z + v2.z, v1.w + v2.w);
        }
        *(float4*)&As[r][c4] = v;
    }

    const int tx = t & 31;
    const int ty = t >> 5;
    float acc[4][4] = {};

    for (int half = 0; half < 2; ++half) {
        __syncthreads();
        for (int i = t * 4; i < 64 * D; i += 256 * 4) {
            *(float4*)&Ws[i] = *(const float4*)&W[half * 64 * D + i];
        }
        __syncthreads();

        for (int k0 = 0; k0 < 64; k0 += 4) {
            float4 a[4];
            #pragma unroll
            for (int i = 0; i < 4; ++i)
                a[i] = *(const float4*)&As[ty * 4 + i][half * 64 + k0];

            #pragma unroll
            for (int kk = 0; kk < 4; ++kk) {
                float4 wv = *(const float4*)&Ws[(k0 + kk) * D + tx * 4];
                #pragma unroll
                for (int i = 0; i < 4; ++i) {
                    float av = (kk == 0) ? a[i].x :
                               (kk == 1) ? a[i].y :
                               (kk == 2) ? a[i].z : a[i].w;
                    acc[i][0] = fmaf(av, wv.x, acc[i][0]);
                    acc[i][1] = fmaf(av, wv.y, acc[i][1]);
                    acc[i][2] = fmaf(av, wv.z, acc[i][2]);
                    acc[i][3] = fmaf(av, wv.w, acc[i][3]);
                }
            }
        }
    }

    float4 bv = *(const float4*)(bias + tx * 4);
    #pragma unroll
    for (int i = 0; i < 4; ++i) {
        int row = row0 + ty * 4 + i;
        if (row < NN) {
            float4 o = make_float4(acc[i][0] + bv.x, acc[i][1] + bv.y,
                                   acc[i][2] + bv.z, acc[i][3] + bv.w);
            if (relu) {
                o.x = fmaxf(0.f, o.x); o.y = fmaxf(0.f, o.y);
                o.z = fmaxf(0.f, o.z); o.w = fmaxf(0.f, o.w);
            }
            *(float4*)(out + (size_t)row * D + tx * 4) = o;
        }
    }
}

extern "C" void kernel_launch(void* const* d_in, const int* in_sizes, int n_in,
                              void* d_out, int out_size, void* d_ws, size_t ws_size,
                              hipStream_t stream)
{
    const float* x   = (const float*)d_in[0];
    const int*   ei  = (const int*)  d_in[1];   // [2, E] int32
    const float* ew  = (const float*)d_in[2];   // [E, 1]
    const float* We1 = (const float*)d_in[3];
    const float* be1 = (const float*)d_in[4];
    const float* W1  = (const float*)d_in[5];
    const float* b1  = (const float*)d_in[6];
    const float* We2 = (const float*)d_in[7];
    const float* be2 = (const float*)d_in[8];
    const float* W2  = (const float*)d_in[9];
    const float* b2  = (const float*)d_in[10];

    float* out = (float*)d_out;          // also holds intermediate h

    // workspace layout (agg first keeps it 16B-aligned for float4)
    float* agg   = (float*)d_ws;                      // NN*D floats (25.6MB)
    u64*   stage = (u64*)(agg + (size_t)NN * D);      // NE u64 (6.4MB)
    int*   G     = (int*)(stage + NE);                // NC*NB
    int*   O     = G + NC * NB;                       // NC*NB
    int*   S     = O + NC * NB;                       // NB
    int*   B     = S + NB;                            // NB+1

    const int* src = ei;
    const int* dst = ei + NE;

    dim3 ggrid((NN + RPB - 1) / RPB);                 // 1563

    // ---- bucket sort build (once; shared by both layers) ----
    hist<<<NC, 256, 0, stream>>>(dst, G);
    colscan<<<(NB + 255) / 256, 256, 0, stream>>>(G, O, S);
    scanS<<<1, 1024, 0, stream>>>(S, B);
    bucket_scatter<<<NC, 256, 0, stream>>>(src, dst, ew, O, B, stage);

    // ---- layer 1 ----
    bucket_aggregate<<<NB, 256, 0, stream>>>(x, B, stage, We1, be1, agg);
    gemm_add_bias<<<ggrid, 256, 0, stream>>>(x, agg, W1, b1, out, 1);

    // ---- layer 2 ----
    bucket_aggregate<<<NB, 256, 0, stream>>>(out, B, stage, We2, be2, agg);
    gemm_add_bias<<<ggrid, 256, 0, stream>>>(out, agg, W2, b2, out, 0);
}

// Round 5
// 322.141 us; speedup vs baseline: 4.8645x; 4.8645x over previous
//
#include <hip/hip_runtime.h>

// GINE 2-layer GNN: N=50000 nodes, E=800000 edges, d=128, f32.
// Round 5: recover round-3 TLP, keep round-4's write-friendly bucket sort.
//  - Round-4 lesson: bucket_aggregate had only 3125 waves (VALUBusy 3.3%,
//    22% occupancy) -> latency-bound disaster. Aggregation must stay
//    per-node gather-parallel (25000 waves).
//  - Build: hist -> colscan -> scanS -> bucket_scatter (contiguous runs,
//    kills the 8x write amplification of the old CSR scatter) ->
//    bucket_csr (per-bucket in-LDS counting sort by node, contiguous
//    writeback, emits per-node offsets). No count_deg, no memsets.
//  - aggregate: 32 lanes/node, 4-deep edge batching (4 gathers in flight).
//  - GEMM unchanged from round 3.

typedef unsigned long long u64;
typedef unsigned int u32;

constexpr int NN = 50000;
constexpr int NE = 800000;
constexpr int D  = 128;
constexpr int RPB = 32;                   // rows per block in the GEMM
constexpr int BSH = 6;                    // 64 nodes per bucket
constexpr int NB  = (NN + 63) >> BSH;     // 782 buckets
constexpr int NC  = 128;                  // edge chunks
constexpr int CHUNK = NE / NC;            // 6250 (exact)
constexpr int BCAP = 4096;                // bucket capacity (mean 1024, >4x)

// pack: [wt f32 (hi32) | 9 spare | d6 (bits 17..22) | src (bits 0..16)]
__device__ __forceinline__ u64 pack_edge(int src, int d6, float w) {
    return ((u64)__float_as_uint(w) << 32) | (u32)(src | (d6 << 17));
}

// ---------------- bucket sort build ----------------

__global__ __launch_bounds__(256) void hist(
    const int* __restrict__ dst, int* __restrict__ G)
{
    __shared__ int hh[NB];
    int t = threadIdx.x, c = blockIdx.x;
    for (int i = t; i < NB; i += 256) hh[i] = 0;
    __syncthreads();
    int e0 = c * CHUNK;
    for (int i = t; i < CHUNK; i += 256)
        atomicAdd(&hh[dst[e0 + i] >> BSH], 1);
    __syncthreads();
    for (int i = t; i < NB; i += 256) G[c * NB + i] = hh[i];
}

__global__ __launch_bounds__(256) void colscan(
    const int* __restrict__ G, int* __restrict__ O, int* __restrict__ S)
{
    int b = blockIdx.x * 256 + threadIdx.x;
    if (b >= NB) return;
    int run = 0;
    #pragma unroll 16
    for (int c = 0; c < NC; ++c) {
        int g = G[c * NB + b];
        O[c * NB + b] = run;
        run += g;
    }
    S[b] = run;
}

// one block: exclusive scan of S[0..NB) -> B, B[NB] = NE
__global__ __launch_bounds__(1024) void scanS(
    const int* __restrict__ S, int* __restrict__ B)
{
    __shared__ int s[1024];
    int t = threadIdx.x;
    int v = (t < NB) ? S[t] : 0;
    s[t] = v;
    __syncthreads();
    for (int d = 1; d < 1024; d <<= 1) {
        int u = (t >= d) ? s[t - d] : 0;
        __syncthreads();
        s[t] += u;
        __syncthreads();
    }
    if (t < NB) B[t] = s[t] - v;
    if (t == 0) B[NB] = NE;
}

__global__ __launch_bounds__(256) void bucket_scatter(
    const int*   __restrict__ src,
    const int*   __restrict__ dst,
    const float* __restrict__ ew,
    const int*   __restrict__ O,
    const int*   __restrict__ B,
    u64*         __restrict__ stage)
{
    __shared__ int base_s[NB];
    __shared__ int cnt_s[NB];
    int t = threadIdx.x, c = blockIdx.x;
    for (int i = t; i < NB; i += 256) {
        base_s[i] = B[i] + O[c * NB + i];
        cnt_s[i]  = 0;
    }
    __syncthreads();
    int e0 = c * CHUNK;
    for (int i = t; i < CHUNK; i += 256) {
        int e  = e0 + i;
        int d  = dst[e];
        int bk = d >> BSH;
        int r  = atomicAdd(&cnt_s[bk], 1);
        stage[base_s[bk] + r] = pack_edge(src[e], d & 63, ew[e]);
    }
}

// one block per bucket: in-LDS counting sort by node, contiguous writeback,
// emit per-node CSR offsets.
__global__ __launch_bounds__(256) void bucket_csr(
    const int* __restrict__ B, u64* __restrict__ stage, int* __restrict__ off)
{
    __shared__ u64 buf[BCAP];           // 32 KB
    __shared__ int cnt[64];
    __shared__ int cur[64];
    __shared__ int noff[64];
    int t = threadIdx.x, b = blockIdx.x;
    int e0 = B[b], e1 = B[b + 1];
    int n = e1 - e0;
    if (n > BCAP) n = BCAP;             // never triggers (mean 1024); OOB guard
    if (t < 64) { cnt[t] = 0; cur[t] = 0; }
    __syncthreads();
    for (int i = t; i < n; i += 256)
        atomicAdd(&cnt[(int)((stage[e0 + i] >> 17) & 63)], 1);
    __syncthreads();
    if (t == 0) {
        int run = 0;
        for (int j = 0; j < 64; ++j) { noff[j] = run; run += cnt[j]; }
    }
    __syncthreads();
    int n0 = b << BSH;
    if (t < 64 && (n0 + t) < NN) off[n0 + t] = e0 + noff[t];
    if (b == NB - 1 && t == 0) off[NN] = NE;
    for (int i = t; i < n; i += 256) {
        u64 p = stage[e0 + i];
        int d6 = (int)((p >> 17) & 63);
        int r = atomicAdd(&cur[d6], 1);
        buf[noff[d6] + r] = p;
    }
    __syncthreads();
    for (int i = t; i < n; i += 256) stage[e0 + i] = buf[i];
}

// ---------------- per-layer aggregate (per-node gather, 4-deep) ----------

__global__ __launch_bounds__(256) void aggregate(
    const float* __restrict__ h,
    const int*   __restrict__ off,
    const u64*   __restrict__ epk,
    const float* __restrict__ We,
    const float* __restrict__ be,
    float*       __restrict__ agg)
{
    int tid = blockIdx.x * 256 + threadIdx.x;
    int n = tid >> 5;
    if (n >= NN) return;
    int d4 = (tid & 31) << 2;

    float4 wv = *(const float4*)(We + d4);
    float4 bv = *(const float4*)(be + d4);

    int e0 = off[n], e1 = off[n + 1];
    float4 acc = make_float4(0.f, 0.f, 0.f, 0.f);

    for (int e = e0; e < e1; e += 4) {
        int m = e1 - e; if (m > 4) m = 4;
        u64 p[4];
        #pragma unroll
        for (int k = 0; k < 4; ++k) p[k] = (k < m) ? epk[e + k] : 0;
        float4 xv[4];
        #pragma unroll
        for (int k = 0; k < 4; ++k) {
            int s = (int)(p[k] & 0x1FFFF);
            xv[k] = *(const float4*)(h + (size_t)s * D + d4);  // 4 in flight
        }
        #pragma unroll
        for (int k = 0; k < 4; ++k) {
            if (k < m) {
                float w = __uint_as_float((u32)(p[k] >> 32));
                acc.x += fmaxf(0.f, xv[k].x + fmaf(w, wv.x, bv.x));
                acc.y += fmaxf(0.f, xv[k].y + fmaf(w, wv.y, bv.y));
                acc.z += fmaxf(0.f, xv[k].z + fmaf(w, wv.z, bv.z));
                acc.w += fmaxf(0.f, xv[k].w + fmaf(w, wv.w, bv.w));
            }
        }
    }
    *(float4*)(agg + (size_t)n * D + d4) = acc;
}

// ---------------- GEMM: out = (relu?)((A1+A2) @ W + bias) ----------------

__global__ __launch_bounds__(256) void gemm_add_bias(
    const float* __restrict__ A1,
    const float* __restrict__ A2,
    const float* __restrict__ W,
    const float* __restrict__ bias,
    float*       __restrict__ out,
    int relu)
{
    __shared__ float Ws[64 * D];        // half of W at a time: 32 KB
    __shared__ float As[RPB][D + 4];

    const int t    = threadIdx.x;
    const int row0 = blockIdx.x * RPB;

    for (int i = t; i < RPB * (D / 4); i += 256) {
        int r   = i >> 5;
        int c4  = (i & 31) << 2;
        int row = row0 + r;
        float4 v = make_float4(0.f, 0.f, 0.f, 0.f);
        if (row < NN) {
            float4 v1 = *(const float4*)(A1 + (size_t)row * D + c4);
            float4 v2 = *(const float4*)(A2 + (size_t)row * D + c4);
            v = make_float4(v1.x + v2.x, v1.y + v2.y, v1.z + v2.z, v1.w + v2.w);
        }
        *(float4*)&As[r][c4] = v;
    }

    const int tx = t & 31;
    const int ty = t >> 5;
    float acc[4][4] = {};

    for (int half = 0; half < 2; ++half) {
        __syncthreads();
        for (int i = t * 4; i < 64 * D; i += 256 * 4) {
            *(float4*)&Ws[i] = *(const float4*)&W[half * 64 * D + i];
        }
        __syncthreads();

        for (int k0 = 0; k0 < 64; k0 += 4) {
            float4 a[4];
            #pragma unroll
            for (int i = 0; i < 4; ++i)
                a[i] = *(const float4*)&As[ty * 4 + i][half * 64 + k0];

            #pragma unroll
            for (int kk = 0; kk < 4; ++kk) {
                float4 wv = *(const float4*)&Ws[(k0 + kk) * D + tx * 4];
                #pragma unroll
                for (int i = 0; i < 4; ++i) {
                    float av = (kk == 0) ? a[i].x :
                               (kk == 1) ? a[i].y :
                               (kk == 2) ? a[i].z : a[i].w;
                    acc[i][0] = fmaf(av, wv.x, acc[i][0]);
                    acc[i][1] = fmaf(av, wv.y, acc[i][1]);
                    acc[i][2] = fmaf(av, wv.z, acc[i][2]);
                    acc[i][3] = fmaf(av, wv.w, acc[i][3]);
                }
            }
        }
    }

    float4 bv = *(const float4*)(bias + tx * 4);
    #pragma unroll
    for (int i = 0; i < 4; ++i) {
        int row = row0 + ty * 4 + i;
        if (row < NN) {
            float4 o = make_float4(acc[i][0] + bv.x, acc[i][1] + bv.y,
                                   acc[i][2] + bv.z, acc[i][3] + bv.w);
            if (relu) {
                o.x = fmaxf(0.f, o.x); o.y = fmaxf(0.f, o.y);
                o.z = fmaxf(0.f, o.z); o.w = fmaxf(0.f, o.w);
            }
            *(float4*)(out + (size_t)row * D + tx * 4) = o;
        }
    }
}

extern "C" void kernel_launch(void* const* d_in, const int* in_sizes, int n_in,
                              void* d_out, int out_size, void* d_ws, size_t ws_size,
                              hipStream_t stream)
{
    const float* x   = (const float*)d_in[0];
    const int*   ei  = (const int*)  d_in[1];   // [2, E] int32
    const float* ew  = (const float*)d_in[2];   // [E, 1]
    const float* We1 = (const float*)d_in[3];
    const float* be1 = (const float*)d_in[4];
    const float* W1  = (const float*)d_in[5];
    const float* b1  = (const float*)d_in[6];
    const float* We2 = (const float*)d_in[7];
    const float* be2 = (const float*)d_in[8];
    const float* W2  = (const float*)d_in[9];
    const float* b2  = (const float*)d_in[10];

    float* out = (float*)d_out;          // also holds intermediate h

    // workspace layout (~33 MB)
    float* agg   = (float*)d_ws;                      // NN*D floats (25.6MB)
    u64*   stage = (u64*)(agg + (size_t)NN * D);      // NE u64 (6.4MB)
    int*   G     = (int*)(stage + NE);                // NC*NB
    int*   O     = G + NC * NB;                       // NC*NB
    int*   S     = O + NC * NB;                       // NB
    int*   B     = S + NB;                            // NB+1
    int*   off   = B + NB + 1;                        // NN+1

    const int* src = ei;
    const int* dst = ei + NE;

    dim3 agrid((NN * 32 + 255) / 256);                // 6250
    dim3 ggrid((NN + RPB - 1) / RPB);                 // 1563

    // ---- bucket-sorted CSR build (once; shared by both layers) ----
    hist<<<NC, 256, 0, stream>>>(dst, G);
    colscan<<<(NB + 255) / 256, 256, 0, stream>>>(G, O, S);
    scanS<<<1, 1024, 0, stream>>>(S, B);
    bucket_scatter<<<NC, 256, 0, stream>>>(src, dst, ew, O, B, stage);
    bucket_csr<<<NB, 256, 0, stream>>>(B, stage, off);

    // ---- layer 1 ----
    aggregate<<<agrid, 256, 0, stream>>>(x, off, stage, We1, be1, agg);
    gemm_add_bias<<<ggrid, 256, 0, stream>>>(x, agg, W1, b1, out, 1);

    // ---- layer 2 ----
    aggregate<<<agrid, 256, 0, stream>>>(out, off, stage, We2, be2, agg);
    gemm_add_bias<<<ggrid, 256, 0, stream>>>(out, agg, W2, b2, out, 0);
}

// Round 6
// 281.472 us; speedup vs baseline: 5.5673x; 1.1445x over previous
//
#include <hip/hip_runtime.h>

// GINE 2-layer GNN: N=50000 nodes, E=800000 edges, d=128.
// Round 6: bf16 feature path (threshold is 15.04 = bf16-grade; f32 floor was
// absmax 2.0). h/x/agg stored bf16 (halves gather footprint: FETCH 177->~95MB),
// GEMMs via mfma_f32_16x16x32_bf16 with A and W^T staged in LDS.
// All accumulation stays f32. Build pipeline unchanged from round 5.

typedef unsigned long long u64;
typedef unsigned int u32;
typedef unsigned short ushort;
typedef __attribute__((ext_vector_type(8))) short short8;
typedef __attribute__((ext_vector_type(4))) float f32x4;

constexpr int NN = 50000;
constexpr int NE = 800000;
constexpr int D  = 128;
constexpr int BSH = 6;                    // 64 nodes per bucket
constexpr int NB  = (NN + 63) >> BSH;     // 782 buckets
constexpr int NC  = 128;                  // edge chunks
constexpr int CHUNK = NE / NC;            // 6250
constexpr int BCAP = 4096;
constexpr int GR = 64;                    // GEMM rows per block
constexpr int GG = (NN + GR - 1) / GR;    // 782

__device__ __forceinline__ ushort f2bf(float f) {
    u32 u = __float_as_uint(f);
    return (ushort)((u + 0x7FFFu + ((u >> 16) & 1u)) >> 16);
}
__device__ __forceinline__ float bf2f(ushort s) {
    return __uint_as_float(((u32)s) << 16);
}
__device__ __forceinline__ u64 pack_edge(int src, int d6, float w) {
    return ((u64)__float_as_uint(w) << 32) | (u32)(src | (d6 << 17));
}

// ---------------- prep: casts ----------------

__global__ __launch_bounds__(256) void cast_x(
    const float* __restrict__ x, ushort* __restrict__ xb)
{
    int i = blockIdx.x * 256 + threadIdx.x;           // 800000 threads
    if (i >= NN * D / 8) return;
    int base = i * 8;
    float4 a = *(const float4*)(x + base);
    float4 b = *(const float4*)(x + base + 4);
    uint4 o;
    o.x = (u32)f2bf(a.x) | ((u32)f2bf(a.y) << 16);
    o.y = (u32)f2bf(a.z) | ((u32)f2bf(a.w) << 16);
    o.z = (u32)f2bf(b.x) | ((u32)f2bf(b.y) << 16);
    o.w = (u32)f2bf(b.z) | ((u32)f2bf(b.w) << 16);
    *(uint4*)(xb + base) = o;
}

// 8 blocks: transpose+cast W (128x128 f32, k-major) -> Wt (n-major bf16)
__global__ __launch_bounds__(256) void prep_w(
    const float* __restrict__ W1, const float* __restrict__ W2,
    ushort* __restrict__ Wt1, ushort* __restrict__ Wt2)
{
    int b = blockIdx.x;
    const float* W  = (b >= 4) ? W2 : W1;
    ushort*      Wt = (b >= 4) ? Wt2 : Wt1;
    int k0 = (b & 3) * 32;
    for (int i = threadIdx.x; i < 32 * D; i += 256) {
        int n = i >> 5, r = i & 31;
        Wt[n * D + k0 + r] = f2bf(W[(k0 + r) * D + n]);
    }
}

// ---------------- bucket sort build (unchanged) ----------------

__global__ __launch_bounds__(256) void hist(
    const int* __restrict__ dst, int* __restrict__ G)
{
    __shared__ int hh[NB];
    int t = threadIdx.x, c = blockIdx.x;
    for (int i = t; i < NB; i += 256) hh[i] = 0;
    __syncthreads();
    int e0 = c * CHUNK;
    for (int i = t; i < CHUNK; i += 256)
        atomicAdd(&hh[dst[e0 + i] >> BSH], 1);
    __syncthreads();
    for (int i = t; i < NB; i += 256) G[c * NB + i] = hh[i];
}

__global__ __launch_bounds__(256) void colscan(
    const int* __restrict__ G, int* __restrict__ O, int* __restrict__ S)
{
    int b = blockIdx.x * 256 + threadIdx.x;
    if (b >= NB) return;
    int run = 0;
    #pragma unroll 16
    for (int c = 0; c < NC; ++c) {
        int g = G[c * NB + b];
        O[c * NB + b] = run;
        run += g;
    }
    S[b] = run;
}

__global__ __launch_bounds__(1024) void scanS(
    const int* __restrict__ S, int* __restrict__ B)
{
    __shared__ int s[1024];
    int t = threadIdx.x;
    int v = (t < NB) ? S[t] : 0;
    s[t] = v;
    __syncthreads();
    for (int d = 1; d < 1024; d <<= 1) {
        int u = (t >= d) ? s[t - d] : 0;
        __syncthreads();
        s[t] += u;
        __syncthreads();
    }
    if (t < NB) B[t] = s[t] - v;
    if (t == 0) B[NB] = NE;
}

__global__ __launch_bounds__(256) void bucket_scatter(
    const int*   __restrict__ src,
    const int*   __restrict__ dst,
    const float* __restrict__ ew,
    const int*   __restrict__ O,
    const int*   __restrict__ B,
    u64*         __restrict__ stage)
{
    __shared__ int base_s[NB];
    __shared__ int cnt_s[NB];
    int t = threadIdx.x, c = blockIdx.x;
    for (int i = t; i < NB; i += 256) {
        base_s[i] = B[i] + O[c * NB + i];
        cnt_s[i]  = 0;
    }
    __syncthreads();
    int e0 = c * CHUNK;
    for (int i = t; i < CHUNK; i += 256) {
        int e  = e0 + i;
        int d  = dst[e];
        int bk = d >> BSH;
        int r  = atomicAdd(&cnt_s[bk], 1);
        stage[base_s[bk] + r] = pack_edge(src[e], d & 63, ew[e]);
    }
}

__global__ __launch_bounds__(256) void bucket_csr(
    const int* __restrict__ B, u64* __restrict__ stage, int* __restrict__ off)
{
    __shared__ u64 buf[BCAP];           // 32 KB
    __shared__ int cnt[64];
    __shared__ int cur[64];
    __shared__ int noff[64];
    int t = threadIdx.x, b = blockIdx.x;
    int e0 = B[b], e1 = B[b + 1];
    int n = e1 - e0;
    if (n > BCAP) n = BCAP;
    if (t < 64) { cnt[t] = 0; cur[t] = 0; }
    __syncthreads();
    for (int i = t; i < n; i += 256)
        atomicAdd(&cnt[(int)((stage[e0 + i] >> 17) & 63)], 1);
    __syncthreads();
    if (t == 0) {
        int run = 0;
        for (int j = 0; j < 64; ++j) { noff[j] = run; run += cnt[j]; }
    }
    __syncthreads();
    int n0 = b << BSH;
    if (t < 64 && (n0 + t) < NN) off[n0 + t] = e0 + noff[t];
    if (b == NB - 1 && t == 0) off[NN] = NE;
    for (int i = t; i < n; i += 256) {
        u64 p = stage[e0 + i];
        int d6 = (int)((p >> 17) & 63);
        int r = atomicAdd(&cur[d6], 1);
        buf[noff[d6] + r] = p;
    }
    __syncthreads();
    for (int i = t; i < n; i += 256) stage[e0 + i] = buf[i];
}

// ------------- per-layer aggregate (bf16 gather, 8-deep, f32 accum) -------

__global__ __launch_bounds__(256) void aggregate(
    const ushort* __restrict__ hb,
    const int*    __restrict__ off,
    const u64*    __restrict__ epk,
    const float*  __restrict__ We,
    const float*  __restrict__ be,
    ushort*       __restrict__ aggb)
{
    int tid = blockIdx.x * 256 + threadIdx.x;
    int n = tid >> 5;
    if (n >= NN) return;
    int d4 = (tid & 31) << 2;

    float4 wv = *(const float4*)(We + d4);
    float4 bv = *(const float4*)(be + d4);

    int e0 = off[n], e1 = off[n + 1];
    float ax = 0.f, ay = 0.f, az = 0.f, aw = 0.f;

    for (int e = e0; e < e1; e += 8) {
        int m = e1 - e; if (m > 8) m = 8;
        u64 p[8];
        #pragma unroll
        for (int k = 0; k < 8; ++k) p[k] = (k < m) ? epk[e + k] : 0;
        uint2 hv[8];
        #pragma unroll
        for (int k = 0; k < 8; ++k) {
            int s = (int)(p[k] & 0x1FFFF);
            hv[k] = *(const uint2*)(hb + (size_t)s * D + d4);  // 8 in flight
        }
        #pragma unroll
        for (int k = 0; k < 8; ++k) {
            if (k < m) {
                float w = __uint_as_float((u32)(p[k] >> 32));
                float hx = __uint_as_float((hv[k].x & 0xFFFFu) << 16);
                float hy = __uint_as_float(hv[k].x & 0xFFFF0000u);
                float hz = __uint_as_float((hv[k].y & 0xFFFFu) << 16);
                float hw = __uint_as_float(hv[k].y & 0xFFFF0000u);
                ax += fmaxf(0.f, hx + fmaf(w, wv.x, bv.x));
                ay += fmaxf(0.f, hy + fmaf(w, wv.y, bv.y));
                az += fmaxf(0.f, hz + fmaf(w, wv.z, bv.z));
                aw += fmaxf(0.f, hw + fmaf(w, wv.w, bv.w));
            }
        }
    }
    uint2 o;
    o.x = (u32)f2bf(ax) | ((u32)f2bf(ay) << 16);
    o.y = (u32)f2bf(az) | ((u32)f2bf(aw) << 16);
    *(uint2*)(aggb + (size_t)n * D + d4) = o;
}

// ---------- MFMA GEMM: out = (relu?)((A1+A2) @ W + bias) ----------
// A1b,A2b bf16 [NN,128]; Wtb = W^T bf16 [n][k]; 64 rows/block.
// Wave w: rows 32*(w>>1) + {0,16}, cols 64*(w&1) + 4 tiles of 16.

__global__ __launch_bounds__(256) void gemm_mfma(
    const ushort* __restrict__ A1b,
    const ushort* __restrict__ A2b,
    const ushort* __restrict__ Wtb,
    const float*  __restrict__ bias,
    float*        __restrict__ outf,   // layer 2 (or null)
    ushort*       __restrict__ outb,   // layer 1 (or null)
    int relu)
{
    __shared__ ushort As[GR * 136];    // rows padded to 136 shorts (2-way free)
    __shared__ ushort Ws[D * 136];

    const int t    = threadIdx.x;
    const int row0 = blockIdx.x * GR;

    // stage A = bf16(f32(A1)+f32(A2)), 8192 elems as uint2 chunks
    for (int c = t; c < GR * (D / 4); c += 256) {
        int r  = c >> 5;
        int k4 = (c & 31) << 2;
        int row = row0 + r;
        uint2 o = make_uint2(0u, 0u);
        if (row < NN) {
            uint2 u1 = *(const uint2*)(A1b + (size_t)row * D + k4);
            uint2 u2 = *(const uint2*)(A2b + (size_t)row * D + k4);
            float s0 = __uint_as_float((u1.x & 0xFFFFu) << 16) + __uint_as_float((u2.x & 0xFFFFu) << 16);
            float s1 = __uint_as_float(u1.x & 0xFFFF0000u)     + __uint_as_float(u2.x & 0xFFFF0000u);
            float s2 = __uint_as_float((u1.y & 0xFFFFu) << 16) + __uint_as_float((u2.y & 0xFFFFu) << 16);
            float s3 = __uint_as_float(u1.y & 0xFFFF0000u)     + __uint_as_float(u2.y & 0xFFFF0000u);
            o.x = (u32)f2bf(s0) | ((u32)f2bf(s1) << 16);
            o.y = (u32)f2bf(s2) | ((u32)f2bf(s3) << 16);
        }
        *(uint2*)&As[r * 136 + k4] = o;
    }
    // stage W^T (16384 shorts)
    for (int c = t; c < D * (D / 4); c += 256) {
        int r  = c >> 5;
        int k4 = (c & 31) << 2;
        *(uint2*)&Ws[r * 136 + k4] = *(const uint2*)(Wtb + r * D + k4);
    }
    __syncthreads();

    const int wave = t >> 6;
    const int lane = t & 63;
    const int q    = lane >> 4;
    const int m    = lane & 15;
    const int wr   = (wave >> 1) * 32;    // row base within block
    const int wc   = (wave & 1) * 64;     // col base

    f32x4 acc[2][4] = {};
    #pragma unroll
    for (int kb = 0; kb < 4; ++kb) {
        int ak = kb * 32 + q * 8;
        short8 af[2];
        #pragma unroll
        for (int rg = 0; rg < 2; ++rg)
            af[rg] = *(const short8*)&As[(wr + rg * 16 + m) * 136 + ak];
        #pragma unroll
        for (int ct = 0; ct < 4; ++ct) {
            short8 bf = *(const short8*)&Ws[(wc + ct * 16 + m) * 136 + ak];
            #pragma unroll
            for (int rg = 0; rg < 2; ++rg)
                acc[rg][ct] = __builtin_amdgcn_mfma_f32_16x16x32_bf16(
                    af[rg], bf, acc[rg][ct], 0, 0, 0);
        }
    }

    #pragma unroll
    for (int ct = 0; ct < 4; ++ct) {
        int col = wc + ct * 16 + m;
        float bc = bias[col];
        #pragma unroll
        for (int rg = 0; rg < 2; ++rg) {
            #pragma unroll
            for (int r = 0; r < 4; ++r) {
                int grow = row0 + wr + rg * 16 + q * 4 + r;
                if (grow < NN) {
                    float v = acc[rg][ct][r] + bc;
                    if (relu) v = fmaxf(0.f, v);
                    if (outb) outb[(size_t)grow * D + col] = f2bf(v);
                    else      outf[(size_t)grow * D + col] = v;
                }
            }
        }
    }
}

extern "C" void kernel_launch(void* const* d_in, const int* in_sizes, int n_in,
                              void* d_out, int out_size, void* d_ws, size_t ws_size,
                              hipStream_t stream)
{
    const float* x   = (const float*)d_in[0];
    const int*   ei  = (const int*)  d_in[1];
    const float* ew  = (const float*)d_in[2];
    const float* We1 = (const float*)d_in[3];
    const float* be1 = (const float*)d_in[4];
    const float* W1  = (const float*)d_in[5];
    const float* b1  = (const float*)d_in[6];
    const float* We2 = (const float*)d_in[7];
    const float* be2 = (const float*)d_in[8];
    const float* W2  = (const float*)d_in[9];
    const float* b2  = (const float*)d_in[10];

    float* out = (float*)d_out;

    // workspace (~46 MB)
    ushort* xb   = (ushort*)d_ws;                    // NN*D bf16 (12.8MB)
    ushort* hb   = xb + (size_t)NN * D;              // NN*D
    ushort* aggb = hb + (size_t)NN * D;              // NN*D
    ushort* Wt1  = aggb + (size_t)NN * D;            // 16384
    ushort* Wt2  = Wt1 + D * D;                      // 16384
    u64*   stage = (u64*)(Wt2 + D * D);              // NE u64 (6.4MB)
    int*   G     = (int*)(stage + NE);               // NC*NB
    int*   O     = G + NC * NB;                      // NC*NB
    int*   S     = O + NC * NB;                      // NB
    int*   B     = S + NB;                           // NB+1
    int*   off   = B + NB + 1;                       // NN+1

    const int* src = ei;
    const int* dst = ei + NE;

    dim3 agrid((NN * 32 + 255) / 256);               // 6250
    dim3 cgrid((NN * D / 8 + 255) / 256);            // 3125

    // ---- prep ----
    cast_x<<<cgrid, 256, 0, stream>>>(x, xb);
    prep_w<<<8, 256, 0, stream>>>(W1, W2, Wt1, Wt2);

    // ---- bucket-sorted CSR build ----
    hist<<<NC, 256, 0, stream>>>(dst, G);
    colscan<<<(NB + 255) / 256, 256, 0, stream>>>(G, O, S);
    scanS<<<1, 1024, 0, stream>>>(S, B);
    bucket_scatter<<<NC, 256, 0, stream>>>(src, dst, ew, O, B, stage);
    bucket_csr<<<NB, 256, 0, stream>>>(B, stage, off);

    // ---- layer 1 ----
    aggregate<<<agrid, 256, 0, stream>>>(xb, off, stage, We1, be1, aggb);
    gemm_mfma<<<GG, 256, 0, stream>>>(xb, aggb, Wt1, b1, nullptr, hb, 1);

    // ---- layer 2 ----
    aggregate<<<agrid, 256, 0, stream>>>(hb, off, stage, We2, be2, aggb);
    gemm_mfma<<<GG, 256, 0, stream>>>(hb, aggb, Wt2, b2, out, nullptr, 0);
}